// Round 9
// baseline (2331.290 us; speedup 1.0000x reference)
//
#include <hip/hip_runtime.h>
#include <stdint.h>

// RNN_Stack: 3-layer leaky-integrator RNN, T=512, B=256, I=64, N=512, TAU=2.
//
// Round-18 = round-1 structure (all-wave independent polling, scattered short
// stores, XCD-clustered mapping — the measured-best skeleton) with:
//   - quad-packed flag lines kept from round 8 (4 sibling counters in one
//     128B line; poller lanes coalesce; passed verification there).
//   - SPECULATIVE STAGING: sample join flags once (non-blocking), issue the
//     staging loads immediately, and accept them if the sample passed --
//     ordering is sound because a passing sample proves the producer's
//     payload had drained to the LLC before our loads were issued. Rare
//     fail -> spin, reload, rewrite LDS (identical to the old serial path).
//     Removes the flag-observe LLC round trip from the serial chain.
//   - round-8's wave-0-only gating and s_sleep are REVERTED (measured
//     regression: extra barrier hop + 64cy sleep quantization).
//   192 blocks = 16 rowgroups x 12 members; 256 thr, 1 wave/SIMD.

#define TS    512
#define BB    256
#define NN    512
#define MR    16     // rows per block
#define NRG   16     // rowgroups
#define NCT   4      // coltiles per layer
#define RD    8      // ring depth (steps)

// swizzled short-index of 16B-chunk c (0..63) in row r (0..15)
#define SW(r, c) (((r) << 9) + ((((c) ^ ((r) & 7))) << 3))

typedef __attribute__((ext_vector_type(8))) short s8v;    // 8 bf16 (4 VGPR)
typedef __attribute__((ext_vector_type(4))) float f4v;    // 4 f32
typedef __attribute__((ext_vector_type(4))) unsigned int u4v;

#define MFMA16(a, b, c) __builtin_amdgcn_mfma_f32_16x16x32_bf16((a), (b), (c), 0, 0, 0)

__device__ __forceinline__ short f2bf(float f) {  // RNE f32 -> bf16 bits
  union { float f; unsigned u; } v; v.f = f;
  unsigned u = v.u;
  u += 0x7fffu + ((u >> 16) & 1u);
  return (short)(u >> 16);
}

__device__ __forceinline__ s8v pack8(f4v a, f4v b) {
  s8v v;
  v[0] = f2bf(a[0]); v[1] = f2bf(a[1]); v[2] = f2bf(a[2]); v[3] = f2bf(a[3]);
  v[4] = f2bf(b[0]); v[5] = f2bf(b[1]); v[6] = f2bf(b[2]); v[7] = f2bf(b[3]);
  return v;
}

__device__ __forceinline__ void waitvm0() {
  asm volatile("s_waitcnt vmcnt(0)" ::: "memory");
}

__device__ __forceinline__ void stg_sc1_b16(unsigned short* p, unsigned v) {
  asm volatile("global_store_short %0, %1, off sc1" :: "v"(p), "v"(v) : "memory");
}
// agent-scope atomics (LLC level) -- the known-good cross-XCD path.
__device__ __forceinline__ unsigned agent_ld(const unsigned* p) {
  return __hip_atomic_load(p, __ATOMIC_RELAXED, __HIP_MEMORY_SCOPE_AGENT);
}
__device__ __forceinline__ void agent_st(unsigned* p, unsigned v) {
  __hip_atomic_store(p, v, __ATOMIC_RELAXED, __HIP_MEMORY_SCOPE_AGENT);
}

// Sync batched sc1 loads, saddr form: dense 1KB/wave per instruction.
// Completed before the asm block exits (early-clobber outs; spill-safe).
__device__ __forceinline__ void ld8_sync(u4v o[8],
    unsigned v0, unsigned v1, unsigned v2, unsigned v3,
    const unsigned short* sq, const unsigned short* sp) {
  asm volatile(
      "global_load_dwordx4 %0, %8, %12 sc1\n\t"
      "global_load_dwordx4 %1, %9, %12 sc1\n\t"
      "global_load_dwordx4 %2, %10, %12 sc1\n\t"
      "global_load_dwordx4 %3, %11, %12 sc1\n\t"
      "global_load_dwordx4 %4, %8, %13 sc1\n\t"
      "global_load_dwordx4 %5, %9, %13 sc1\n\t"
      "global_load_dwordx4 %6, %10, %13 sc1\n\t"
      "global_load_dwordx4 %7, %11, %13 sc1\n\t"
      "s_waitcnt vmcnt(0)"
      : "=&v"(o[0]), "=&v"(o[1]), "=&v"(o[2]), "=&v"(o[3]),
        "=&v"(o[4]), "=&v"(o[5]), "=&v"(o[6]), "=&v"(o[7])
      : "v"(v0), "v"(v1), "v"(v2), "v"(v3), "s"(sq), "s"(sp)
      : "memory");
}
__device__ __forceinline__ void ld4_sync(u4v o[4],
    unsigned v0, unsigned v1, unsigned v2, unsigned v3,
    const unsigned short* sb) {
  asm volatile(
      "global_load_dwordx4 %0, %4, %8 sc1\n\t"
      "global_load_dwordx4 %1, %5, %8 sc1\n\t"
      "global_load_dwordx4 %2, %6, %8 sc1\n\t"
      "global_load_dwordx4 %3, %7, %8 sc1\n\t"
      "s_waitcnt vmcnt(0)"
      : "=&v"(o[0]), "=&v"(o[1]), "=&v"(o[2]), "=&v"(o[3])
      : "v"(v0), "v"(v1), "v"(v2), "v"(v3), "s"(sb)
      : "memory");
}

__global__ __launch_bounds__(256, 1) void rnn_pipe(
    const float* __restrict__ data, const float* __restrict__ h0,
    const float* __restrict__ Win,  const float* __restrict__ b_in,
    const float* __restrict__ Whh,  const float* __restrict__ b_hh,
    const float* __restrict__ Whi,  const float* __restrict__ b_hi,
    unsigned short* __restrict__ ring, unsigned* __restrict__ cnt,
    float* __restrict__ hfinal)
{
  __shared__ __attribute__((aligned(16))) unsigned short qtile[MR * NN];
  __shared__ __attribute__((aligned(16))) unsigned short ptile[MR * NN];

  const int bi   = blockIdx.x;
  // XCD-clustered role mapping (round-1 measured: weight L2 locality win).
  const int x8   = bi & 7;
  const int rr   = bi >> 3;            // 0..23
  const int half = (rr >= 12) ? 1 : 0;
  const int m    = rr - half * 12;     // member 0..11 within the rowgroup
  const int rg   = x8 * 2 + half;
  const int lay  = m >> 2;
  const int ct   = m & 3;
  const int tid  = threadIdx.x;
  const int wv   = tid >> 6;
  const int lane = tid & 63;
  const int lo   = lane & 15;
  const int q4   = lane >> 4;
  const int row0 = rg * MR;
  const int cw   = ct * 128 + wv * 32;   // this wave's 32-col base

  // ---- flags, quad-packed: one 128B line per (lay,rg) quad --------------
  //   prod line  idx = lay*NRG+rg        (dwords 0..3 = ct)
  //   done line  idx = 64 + lay*NRG+rg   (dwords 0..3 = ct; lay>0 only)
  unsigned* prodline = cnt + (size_t)(lay * NRG + rg) * 32;
  unsigned* doneline = cnt + (size_t)(64 + lay * NRG + rg) * 32;

  // all-wave poll assignment (round-1 structure): lanes 0-3 q-join,
  // 4-7 p-join, 8-11 backpressure; other lanes idle (no load).
  unsigned* pollptr = cnt;
  int polltype = 0;
  if (lane < 4) {
    pollptr = cnt + (size_t)(lay * NRG + rg) * 32 + lane;                  polltype = 1;
  } else if (lane >= 4 && lane < 8 && lay > 0) {
    pollptr = cnt + (size_t)((lay - 1) * NRG + rg) * 32 + (lane - 4);      polltype = 2;
  } else if (lane >= 8 && lane < 12 && lay < 2) {
    pollptr = cnt + (size_t)(64 + (lay + 1) * NRG + rg) * 32 + (lane - 8); polltype = 3;
  }

  // ---- weight preload: B-frag[k = kk*32 + q4*8 + j][col = cw + nf*16 + lo] ----
  s8v WH[16][2];            // Whh_lay (diag zeroed)
  s8v WI[16][2];            // Whi_{lay-1} (lay>0)
  s8v WX[2][2];             // Win (K=64)
  float biasv[2];
  f4v  hst[2];              // f32 h-state, C-layout rows q4*4+r, cols cw+nf*16+lo

  {
    const float* WmH = Whh + (size_t)lay * NN * NN;
    #pragma unroll
    for (int kk = 0; kk < 16; ++kk) {
      #pragma unroll
      for (int nf = 0; nf < 2; ++nf) {
        const int col = cw + nf * 16 + lo;
        s8v v;
        #pragma unroll
        for (int j = 0; j < 8; ++j) {
          const int k = kk * 32 + q4 * 8 + j;
          float f = WmH[(size_t)k * NN + col];
          if (k == col) f = 0.f;            // forward() zeroes recurrent diag
          v[j] = f2bf(f);
        }
        WH[kk][nf] = v;
      }
    }
    if (lay > 0) {
      const float* WmI = Whi + (size_t)(lay - 1) * NN * NN;
      #pragma unroll
      for (int kk = 0; kk < 16; ++kk) {
        #pragma unroll
        for (int nf = 0; nf < 2; ++nf) {
          const int col = cw + nf * 16 + lo;
          s8v v;
          #pragma unroll
          for (int j = 0; j < 8; ++j)
            v[j] = f2bf(WmI[(size_t)(kk * 32 + q4 * 8 + j) * NN + col]);
          WI[kk][nf] = v;
        }
      }
    }
    #pragma unroll
    for (int kk = 0; kk < 2; ++kk) {
      #pragma unroll
      for (int nf = 0; nf < 2; ++nf) {
        const int col = cw + nf * 16 + lo;
        s8v v;
        #pragma unroll
        for (int j = 0; j < 8; ++j)
          v[j] = f2bf(Win[(size_t)(kk * 32 + q4 * 8 + j) * NN + col]);
        WX[kk][nf] = v;
      }
    }
    #pragma unroll
    for (int nf = 0; nf < 2; ++nf) {
      const int col = cw + nf * 16 + lo;
      float b = b_hh[lay * NN + col] + b_in[col];
      if (lay > 0) b += b_hi[(lay - 1) * NN + col];
      biasv[nf] = b;
      #pragma unroll
      for (int r = 0; r < 4; ++r)
        hst[nf][r] = h0[(size_t)lay * BB * NN + (size_t)(row0 + q4 * 4 + r) * NN + col];
    }
  }

  const size_t myring = (size_t)(lay * NRG + rg) * RD;
  const size_t upring = (size_t)((lay - 1) * NRG + rg) * RD;

  // loop-invariant staging byte-offsets: chunk g = i*256 + tid (dense 1KB/wave)
  unsigned voff0 = (unsigned)((0 * 256 + tid) * 16);
  unsigned voff1 = (unsigned)((1 * 256 + tid) * 16);
  unsigned voff2 = (unsigned)((2 * 256 + tid) * 16);
  unsigned voff3 = (unsigned)((3 * 256 + tid) * 16);

  // ---- xa preload for t=0 ----
  f4v xa0, xa1, xa2, xa3;
  {
    const float* dsrc = data + ((size_t)0 * BB + row0 + lo) * 64 + q4 * 8;
    xa0 = *(const f4v*)(dsrc + 0);
    xa1 = *(const f4v*)(dsrc + 4);
    xa2 = *(const f4v*)(dsrc + 32);
    xa3 = *(const f4v*)(dsrc + 36);
  }

  for (int t = 0; t < TS; ++t) {
    // ---- x-part MFMAs BEFORE the join (xa loaded under previous drain) ----
    f4v zero4 = {0.f, 0.f, 0.f, 0.f};
    f4v accQ[2] = {zero4, zero4};
    f4v accP[2] = {zero4, zero4};
    {
      s8v xv0 = pack8(xa0, xa1);
      s8v xv1 = pack8(xa2, xa3);
      accQ[0] = MFMA16(xv0, WX[0][0], accQ[0]);
      accQ[1] = MFMA16(xv0, WX[0][1], accQ[1]);
      accQ[0] = MFMA16(xv1, WX[1][0], accQ[0]);
      accQ[1] = MFMA16(xv1, WX[1][1], accQ[1]);
    }

    // ---- join targets ----
    unsigned tgt = 0;
    if (polltype == 1) tgt = (unsigned)t;                                  // q-join
    else if (polltype == 2) tgt = (unsigned)(t + 1);                       // p-join
    else if (polltype == 3 && t >= RD) tgt = (unsigned)(t - RD + 1);       // backpressure
    // non-blocking sample; a pass means staging loads issued below are valid
    unsigned sv = tgt;
    if (polltype) sv = agent_ld(pollptr);
    const int pass = __all((int)(sv >= tgt));

    // ---- staging (speculative): loads + swizzled LDS writes ----
    const unsigned short* qsrc = ring + (myring + ((t - 1) & (RD - 1))) * (MR * NN);
    const unsigned short* psrc = ring + (upring + (t & (RD - 1))) * (MR * NN);
    auto do_stage = [&]() {
      u4v st[8];
      if (t >= 1 && lay > 0) {
        ld8_sync(st, voff0, voff1, voff2, voff3, qsrc, psrc);
        #pragma unroll
        for (int i = 0; i < 4; ++i) {
          const int g = i * 256 + tid;
          const int r = g >> 6, c = g & 63;
          *(u4v*)(qtile + SW(r, c)) = st[i];
          *(u4v*)(ptile + SW(r, c)) = st[4 + i];
        }
      } else if (t >= 1) {
        ld4_sync(st, voff0, voff1, voff2, voff3, qsrc);
        #pragma unroll
        for (int i = 0; i < 4; ++i) {
          const int g = i * 256 + tid;
          const int r = g >> 6, c = g & 63;
          *(u4v*)(qtile + SW(r, c)) = st[i];
        }
      } else if (lay > 0) {
        ld4_sync(st, voff0, voff1, voff2, voff3, psrc);
        #pragma unroll
        for (int i = 0; i < 4; ++i) {
          const int g = i * 256 + tid;
          const int r = g >> 6, c = g & 63;
          *(u4v*)(ptile + SW(r, c)) = st[i];
        }
      }
    };
    do_stage();
    if (!pass) {
      // slow path: authoritative poll, then reload fresh data over the stale
      for (;;) {
        unsigned v = tgt;
        if (polltype) v = agent_ld(pollptr);
        if (__all((int)(v >= tgt))) break;
      }
      do_stage();
    }
    __syncthreads();   // staging visible to all waves
    if (tid == 0 && lay > 0)   // upstream slot t consumed into LDS
      agent_st(doneline + ct, (unsigned)(t + 1));

    // ---- MFMA phase: q + p from swizzled LDS (t=0 q from h0) ----
    if (lay > 0) {
      #pragma unroll
      for (int kk = 0; kk < 16; ++kk) {
        s8v av = *(const s8v*)(ptile + SW(lo, kk * 4 + q4));
        accP[0] = MFMA16(av, WI[kk][0], accP[0]);
        accP[1] = MFMA16(av, WI[kk][1], accP[1]);
      }
    }
    if (t == 0) {
      const float* hsrc = h0 + (size_t)lay * BB * NN + (size_t)(row0 + lo) * NN + q4 * 8;
      #pragma unroll
      for (int kk = 0; kk < 16; ++kk) {
        f4v a = *(const f4v*)(hsrc + kk * 32);
        f4v b = *(const f4v*)(hsrc + kk * 32 + 4);
        s8v av = pack8(a, b);
        accQ[0] = MFMA16(av, WH[kk][0], accQ[0]);
        accQ[1] = MFMA16(av, WH[kk][1], accQ[1]);
      }
    } else {
      #pragma unroll
      for (int kk = 0; kk < 16; ++kk) {
        s8v av = *(const s8v*)(qtile + SW(lo, kk * 4 + q4));
        accQ[0] = MFMA16(av, WH[kk][0], accQ[0]);
        accQ[1] = MFMA16(av, WH[kk][1], accQ[1]);
      }
    }

    // ---- combine + produce: n = lrelu(0.5*h + 0.5*(q+p+x+bias)) ----
    {
      unsigned short* rslot = ring + (myring + (t & (RD - 1))) * (MR * NN);
      #pragma unroll
      for (int nf = 0; nf < 2; ++nf) {
        const int col = cw + nf * 16 + lo;
        #pragma unroll
        for (int r = 0; r < 4; ++r) {
          const int row = q4 * 4 + r;
          float v = 0.5f * hst[nf][r] + 0.5f * (accQ[nf][r] + accP[nf][r] + biasv[nf]);
          v = (v >= 0.f) ? v : 0.01f * v;
          hst[nf][r] = v;
          stg_sc1_b16(rslot + (size_t)row * NN + col,
                      (unsigned)(unsigned short)f2bf(v));
          if (lay == 2 && t == TS - 1)
            hfinal[(size_t)(row0 + row) * NN + col] = v;
        }
      }
    }

    // ---- xa loads for t+1 (latency hidden under the store drain) ----
    {
      const int tn = (t + 1 < TS) ? t + 1 : t;
      const float* dsrc = data + ((size_t)tn * BB + row0 + lo) * 64 + q4 * 8;
      xa0 = *(const f4v*)(dsrc + 0);
      xa1 = *(const f4v*)(dsrc + 4);
      xa2 = *(const f4v*)(dsrc + 32);
      xa3 = *(const f4v*)(dsrc + 36);
    }
    waitvm0();         // drains payload stores (and xa loads)
    __syncthreads();   // every wave's stores drained -> publish
    if (tid == 0)
      agent_st(prodline + ct, (unsigned)(t + 1));
  }
}

// out[256,10] = hfinal @ Wfc + b_fc   (tiny f32 readout)
__global__ void readout_k(const float* __restrict__ hfinal, const float* __restrict__ Wfc,
                          const float* __restrict__ b_fc, float* __restrict__ out)
{
  const int row = blockIdx.x;
  const int lane = threadIdx.x;  // 64
  float a[10];
  #pragma unroll
  for (int c = 0; c < 10; ++c) a[c] = 0.f;
  for (int k = lane; k < NN; k += 64) {
    const float h = hfinal[(size_t)row * NN + k];
    const float* w = Wfc + (size_t)k * 10;
    #pragma unroll
    for (int c = 0; c < 10; ++c) a[c] += h * w[c];
  }
  #pragma unroll
  for (int off = 32; off > 0; off >>= 1) {
    #pragma unroll
    for (int c = 0; c < 10; ++c) a[c] += __shfl_down(a[c], off);
  }
  if (lane == 0) {
    #pragma unroll
    for (int c = 0; c < 10; ++c) out[row * 10 + c] = a[c] + b_fc[c];
  }
}

extern "C" void kernel_launch(void* const* d_in, const int* in_sizes, int n_in,
                              void* d_out, int out_size, void* d_ws, size_t ws_size,
                              hipStream_t stream) {
  (void)in_sizes; (void)n_in; (void)out_size; (void)ws_size;
  const float* data = (const float*)d_in[0];
  const float* h0   = (const float*)d_in[1];
  const float* Win  = (const float*)d_in[2];
  const float* b_in = (const float*)d_in[3];
  const float* Whh  = (const float*)d_in[4];
  const float* b_hh = (const float*)d_in[5];
  const float* Whi  = (const float*)d_in[6];
  const float* b_hi = (const float*)d_in[7];
  const float* Wfc  = (const float*)d_in[8];
  const float* b_fc = (const float*)d_in[9];

  // ws: rings (3 lay x 16 rg x RD x 16KB = 6 MB) | flags 64KB | hfinal 512KB
  unsigned short* ring = (unsigned short*)d_ws;
  const size_t ring_bytes = (size_t)3 * NRG * RD * MR * NN * 2;  // 6 MB
  unsigned* cnt = (unsigned*)((char*)d_ws + ring_bytes);
  float* hfinal = (float*)((char*)d_ws + ring_bytes + 65536);

  hipMemsetAsync(cnt, 0, 65536, stream);   // flags MUST start at 0 (ws is poisoned)
  hipLaunchKernelGGL(rnn_pipe, dim3(192), dim3(256), 0, stream,
                     data, h0, Win, b_in, Whh, b_hh, Whi, b_hi, ring, cnt, hfinal);
  hipLaunchKernelGGL(readout_k, dim3(256), dim3(64), 0, stream,
                     hfinal, Wfc, b_fc, (float*)d_out);
}

// Round 10
// 1979.619 us; speedup vs baseline: 1.1776x; 1.1776x over previous
//
#include <hip/hip_runtime.h>
#include <stdint.h>

// RNN_Stack: 3-layer leaky-integrator RNN, T=512, B=256, I=64, N=512, TAU=2.
//
// Round-19 = round-1 protocol (best measured: 2063 us steady) with the block
// geometry restructured 256 -> 512 threads (8 waves x 16 cols instead of
// 4 waves x 32 cols):
//   - kills the register-file overflow: weights per wave drop from 272+
//     VGPRs (WH[16][2]+WI[16][2]+WX, > 256 ceiling -> AGPR/scratch traffic
//     on the MFMA dependency path every step) to ~136 (WH[16]+WI[16]+WX[2]).
//   - 2 waves/SIMD: one wave's LLC stalls host the sibling wave's issue
//     (m114 overlap mechanism, unavailable at 1 wave/SIMD).
//   Flag layout, ring layout, poll scheme, staging volume: identical to
//   round-1. 192 blocks = 16 rowgroups x 12 members; 512 thr.

#define TS    512
#define BB    256
#define NN    512
#define MR    16     // rows per block
#define NRG   16     // rowgroups
#define NCT   4      // coltiles per layer
#define RD    8      // ring depth (steps)

// swizzled short-index of 16B-chunk c (0..63) in row r (0..15)
#define SW(r, c) (((r) << 9) + ((((c) ^ ((r) & 7))) << 3))

typedef __attribute__((ext_vector_type(8))) short s8v;    // 8 bf16 (4 VGPR)
typedef __attribute__((ext_vector_type(4))) float f4v;    // 4 f32
typedef __attribute__((ext_vector_type(4))) unsigned int u4v;

#define MFMA16(a, b, c) __builtin_amdgcn_mfma_f32_16x16x32_bf16((a), (b), (c), 0, 0, 0)

__device__ __forceinline__ short f2bf(float f) {  // RNE f32 -> bf16 bits
  union { float f; unsigned u; } v; v.f = f;
  unsigned u = v.u;
  u += 0x7fffu + ((u >> 16) & 1u);
  return (short)(u >> 16);
}

__device__ __forceinline__ s8v pack8(f4v a, f4v b) {
  s8v v;
  v[0] = f2bf(a[0]); v[1] = f2bf(a[1]); v[2] = f2bf(a[2]); v[3] = f2bf(a[3]);
  v[4] = f2bf(b[0]); v[5] = f2bf(b[1]); v[6] = f2bf(b[2]); v[7] = f2bf(b[3]);
  return v;
}

__device__ __forceinline__ void waitvm0() {
  asm volatile("s_waitcnt vmcnt(0)" ::: "memory");
}

__device__ __forceinline__ void stg_sc1_b16(unsigned short* p, unsigned v) {
  asm volatile("global_store_short %0, %1, off sc1" :: "v"(p), "v"(v) : "memory");
}
// agent-scope atomics (LLC level) -- the known-good cross-XCD path.
__device__ __forceinline__ unsigned agent_ld(const unsigned* p) {
  return __hip_atomic_load(p, __ATOMIC_RELAXED, __HIP_MEMORY_SCOPE_AGENT);
}
__device__ __forceinline__ void agent_st(unsigned* p, unsigned v) {
  __hip_atomic_store(p, v, __ATOMIC_RELAXED, __HIP_MEMORY_SCOPE_AGENT);
}

// Sync batched sc1 loads, saddr form (512-thread geometry: 2 chunks per
// thread per tile). Completed before the asm block exits.
__device__ __forceinline__ void ld4_dual(u4v o[4],
    unsigned vA, unsigned vB,
    const unsigned short* sq, const unsigned short* sp) {
  asm volatile(
      "global_load_dwordx4 %0, %4, %6 sc1\n\t"
      "global_load_dwordx4 %1, %5, %6 sc1\n\t"
      "global_load_dwordx4 %2, %4, %7 sc1\n\t"
      "global_load_dwordx4 %3, %5, %7 sc1\n\t"
      "s_waitcnt vmcnt(0)"
      : "=&v"(o[0]), "=&v"(o[1]), "=&v"(o[2]), "=&v"(o[3])
      : "v"(vA), "v"(vB), "s"(sq), "s"(sp)
      : "memory");
}
__device__ __forceinline__ void ld2_sync(u4v o[2],
    unsigned vA, unsigned vB, const unsigned short* sb) {
  asm volatile(
      "global_load_dwordx4 %0, %2, %4 sc1\n\t"
      "global_load_dwordx4 %1, %3, %4 sc1\n\t"
      "s_waitcnt vmcnt(0)"
      : "=&v"(o[0]), "=&v"(o[1])
      : "v"(vA), "v"(vB), "s"(sb)
      : "memory");
}

__global__ __launch_bounds__(512, 2) void rnn_pipe(
    const float* __restrict__ data, const float* __restrict__ h0,
    const float* __restrict__ Win,  const float* __restrict__ b_in,
    const float* __restrict__ Whh,  const float* __restrict__ b_hh,
    const float* __restrict__ Whi,  const float* __restrict__ b_hi,
    unsigned short* __restrict__ ring, unsigned* __restrict__ cnt,
    float* __restrict__ hfinal)
{
  __shared__ __attribute__((aligned(16))) unsigned short qtile[MR * NN];
  __shared__ __attribute__((aligned(16))) unsigned short ptile[MR * NN];

  const int bi   = blockIdx.x;
  // XCD-clustered role mapping (round-1 measured: weight L2 locality win).
  const int x8   = bi & 7;
  const int rr   = bi >> 3;            // 0..23
  const int half = (rr >= 12) ? 1 : 0;
  const int m    = rr - half * 12;     // member 0..11 within the rowgroup
  const int rg   = x8 * 2 + half;
  const int lay  = m >> 2;
  const int ct   = m & 3;
  const int tid  = threadIdx.x;        // 0..511
  const int wv   = tid >> 6;           // 0..7
  const int lane = tid & 63;
  const int lo   = lane & 15;
  const int q4   = lane >> 4;
  const int row0 = rg * MR;
  const int cw   = ct * 128 + wv * 16;   // this wave's 16-col base

  // ---- flags: prod[idx], done[idx] at 128B stride; idx=(lay*16+rg)*4+ct ----
  const int sidx = (lay * NRG + rg) * NCT + ct;
  unsigned* selfprod = cnt + (size_t)sidx * 32;
  unsigned* selfdone = cnt + (size_t)(256 + sidx) * 32;

  // per-lane poll assignment (lanes 0-3: q-join, 4-7: p-join, 8-11: backpressure)
  unsigned* pollptr = selfprod;   // dummy (target stays satisfied)
  int polltype = 0;
  if (lane < 4) {
    pollptr = cnt + (size_t)((lay * NRG + rg) * NCT + lane) * 32;  polltype = 1;
  } else if (lane >= 4 && lane < 8 && lay > 0) {
    pollptr = cnt + (size_t)(((lay - 1) * NRG + rg) * NCT + (lane - 4)) * 32;  polltype = 2;
  } else if (lane >= 8 && lane < 12 && lay < 2) {
    pollptr = cnt + (size_t)(256 + ((lay + 1) * NRG + rg) * NCT + (lane - 8)) * 32;  polltype = 3;
  }

  // ---- weight preload: B-frag[k = kk*32 + q4*8 + j][col = cw + lo] ----
  s8v WH[16];               // Whh_lay (diag zeroed)      64 VGPR
  s8v WI[16];               // Whi_{lay-1} (lay>0)        64 VGPR
  s8v WX[2];                // Win (K=64)                  8 VGPR
  float biasv;
  f4v  hst;                 // f32 h-state, rows q4*4+r, col cw+lo

  {
    const float* WmH = Whh + (size_t)lay * NN * NN;
    const int col = cw + lo;
    #pragma unroll
    for (int kk = 0; kk < 16; ++kk) {
      s8v v;
      #pragma unroll
      for (int j = 0; j < 8; ++j) {
        const int k = kk * 32 + q4 * 8 + j;
        float f = WmH[(size_t)k * NN + col];
        if (k == col) f = 0.f;            // forward() zeroes recurrent diag
        v[j] = f2bf(f);
      }
      WH[kk] = v;
    }
    if (lay > 0) {
      const float* WmI = Whi + (size_t)(lay - 1) * NN * NN;
      #pragma unroll
      for (int kk = 0; kk < 16; ++kk) {
        s8v v;
        #pragma unroll
        for (int j = 0; j < 8; ++j)
          v[j] = f2bf(WmI[(size_t)(kk * 32 + q4 * 8 + j) * NN + col]);
        WI[kk] = v;
      }
    }
    #pragma unroll
    for (int kk = 0; kk < 2; ++kk) {
      s8v v;
      #pragma unroll
      for (int j = 0; j < 8; ++j)
        v[j] = f2bf(Win[(size_t)(kk * 32 + q4 * 8 + j) * NN + col]);
      WX[kk] = v;
    }
    float b = b_hh[lay * NN + col] + b_in[col];
    if (lay > 0) b += b_hi[(lay - 1) * NN + col];
    biasv = b;
    #pragma unroll
    for (int r = 0; r < 4; ++r)
      hst[r] = h0[(size_t)lay * BB * NN + (size_t)(row0 + q4 * 4 + r) * NN + col];
  }

  const size_t myring = (size_t)(lay * NRG + rg) * RD;
  const size_t upring = (size_t)((lay - 1) * NRG + rg) * RD;

  // loop-invariant staging byte-offsets: chunk g = i*512 + tid (dense, 512 thr)
  unsigned voffA = (unsigned)((0 * 512 + tid) * 16);
  unsigned voffB = (unsigned)((1 * 512 + tid) * 16);
  const int gA_r = tid >> 6,           gA_c = tid & 63;
  const int gB_r = (512 + tid) >> 6,   gB_c = tid & 63;   // (512+tid)&63 == tid&63

  // ---- xa preload for t=0 (A-frag is wave-independent) ----
  f4v xa0, xa1, xa2, xa3;
  {
    const float* dsrc = data + ((size_t)0 * BB + row0 + lo) * 64 + q4 * 8;
    xa0 = *(const f4v*)(dsrc + 0);
    xa1 = *(const f4v*)(dsrc + 4);
    xa2 = *(const f4v*)(dsrc + 32);
    xa3 = *(const f4v*)(dsrc + 36);
  }

  for (int t = 0; t < TS; ++t) {
    // ---- x-part MFMAs BEFORE the poll (xa loaded under previous drain) ----
    f4v zero4 = {0.f, 0.f, 0.f, 0.f};
    f4v accQ = zero4;
    f4v accP = zero4;
    {
      s8v xv0 = pack8(xa0, xa1);
      s8v xv1 = pack8(xa2, xa3);
      accQ = MFMA16(xv0, WX[0], accQ);
      accQ = MFMA16(xv1, WX[1], accQ);
    }

    // ---- poll all join conditions in parallel across lanes ----
    unsigned tgt = 0;
    if (polltype == 1) tgt = (unsigned)t;                                  // q-join
    else if (polltype == 2) tgt = (unsigned)(t + 1);                       // p-join
    else if (polltype == 3 && t >= RD) tgt = (unsigned)(t - RD + 1);       // backpressure
    for (;;) {
      unsigned v = agent_ld(pollptr);
      if (__all((int)(v >= tgt))) break;
    }

    // ---- cooperative staging: ONE sync asm block, swizzled LDS writes ----
    {
      const unsigned short* qsrc = ring + (myring + ((t - 1) & (RD - 1))) * (MR * NN);
      const unsigned short* psrc = ring + (upring + (t & (RD - 1))) * (MR * NN);
      if (t >= 1 && lay > 0) {
        u4v st[4];
        ld4_dual(st, voffA, voffB, qsrc, psrc);
        *(u4v*)(qtile + SW(gA_r, gA_c)) = st[0];
        *(u4v*)(qtile + SW(gB_r, gB_c)) = st[1];
        *(u4v*)(ptile + SW(gA_r, gA_c)) = st[2];
        *(u4v*)(ptile + SW(gB_r, gB_c)) = st[3];
      } else if (t >= 1) {
        u4v st[2];
        ld2_sync(st, voffA, voffB, qsrc);
        *(u4v*)(qtile + SW(gA_r, gA_c)) = st[0];
        *(u4v*)(qtile + SW(gB_r, gB_c)) = st[1];
      } else if (lay > 0) {
        u4v st[2];
        ld2_sync(st, voffA, voffB, psrc);
        *(u4v*)(ptile + SW(gA_r, gA_c)) = st[0];
        *(u4v*)(ptile + SW(gB_r, gB_c)) = st[1];
      }
    }
    __syncthreads();   // staging visible to all waves
    if (tid == 0 && lay > 0)   // upstream slot t consumed into LDS
      agent_st(selfdone, (unsigned)(t + 1));

    // ---- MFMA phase: q + p from swizzled LDS (t=0 q from h0) ----
    if (lay > 0) {
      #pragma unroll
      for (int kk = 0; kk < 16; ++kk) {
        s8v av = *(const s8v*)(ptile + SW(lo, kk * 4 + q4));
        accP = MFMA16(av, WI[kk], accP);
      }
    }
    if (t == 0) {
      const float* hsrc = h0 + (size_t)lay * BB * NN + (size_t)(row0 + lo) * NN + q4 * 8;
      #pragma unroll
      for (int kk = 0; kk < 16; ++kk) {
        f4v a = *(const f4v*)(hsrc + kk * 32);
        f4v b = *(const f4v*)(hsrc + kk * 32 + 4);
        s8v av = pack8(a, b);
        accQ = MFMA16(av, WH[kk], accQ);
      }
    } else {
      #pragma unroll
      for (int kk = 0; kk < 16; ++kk) {
        s8v av = *(const s8v*)(qtile + SW(lo, kk * 4 + q4));
        accQ = MFMA16(av, WH[kk], accQ);
      }
    }

    // ---- combine + produce: n = lrelu(0.5*h + 0.5*(q+p+x+bias)) ----
    {
      unsigned short* rslot = ring + (myring + (t & (RD - 1))) * (MR * NN);
      const int col = cw + lo;
      #pragma unroll
      for (int r = 0; r < 4; ++r) {
        const int row = q4 * 4 + r;
        float v = 0.5f * hst[r] + 0.5f * (accQ[r] + accP[r] + biasv);
        v = (v >= 0.f) ? v : 0.01f * v;
        hst[r] = v;
        stg_sc1_b16(rslot + (size_t)row * NN + col,
                    (unsigned)(unsigned short)f2bf(v));
        if (lay == 2 && t == TS - 1)
          hfinal[(size_t)(row0 + row) * NN + col] = v;
      }
    }

    // ---- xa loads for t+1 (latency hidden under the store drain) ----
    {
      const int tn = (t + 1 < TS) ? t + 1 : t;
      const float* dsrc = data + ((size_t)tn * BB + row0 + lo) * 64 + q4 * 8;
      xa0 = *(const f4v*)(dsrc + 0);
      xa1 = *(const f4v*)(dsrc + 4);
      xa2 = *(const f4v*)(dsrc + 32);
      xa3 = *(const f4v*)(dsrc + 36);
    }
    waitvm0();         // drains payload stores (and xa loads)
    __syncthreads();   // every wave's stores drained -> publish
    if (tid == 0)
      agent_st(selfprod, (unsigned)(t + 1));
  }
}

// out[256,10] = hfinal @ Wfc + b_fc   (tiny f32 readout)
__global__ void readout_k(const float* __restrict__ hfinal, const float* __restrict__ Wfc,
                          const float* __restrict__ b_fc, float* __restrict__ out)
{
  const int row = blockIdx.x;
  const int lane = threadIdx.x;  // 64
  float a[10];
  #pragma unroll
  for (int c = 0; c < 10; ++c) a[c] = 0.f;
  for (int k = lane; k < NN; k += 64) {
    const float h = hfinal[(size_t)row * NN + k];
    const float* w = Wfc + (size_t)k * 10;
    #pragma unroll
    for (int c = 0; c < 10; ++c) a[c] += h * w[c];
  }
  #pragma unroll
  for (int off = 32; off > 0; off >>= 1) {
    #pragma unroll
    for (int c = 0; c < 10; ++c) a[c] += __shfl_down(a[c], off);
  }
  if (lane == 0) {
    #pragma unroll
    for (int c = 0; c < 10; ++c) out[row * 10 + c] = a[c] + b_fc[c];
  }
}

extern "C" void kernel_launch(void* const* d_in, const int* in_sizes, int n_in,
                              void* d_out, int out_size, void* d_ws, size_t ws_size,
                              hipStream_t stream) {
  (void)in_sizes; (void)n_in; (void)out_size; (void)ws_size;
  const float* data = (const float*)d_in[0];
  const float* h0   = (const float*)d_in[1];
  const float* Win  = (const float*)d_in[2];
  const float* b_in = (const float*)d_in[3];
  const float* Whh  = (const float*)d_in[4];
  const float* b_hh = (const float*)d_in[5];
  const float* Whi  = (const float*)d_in[6];
  const float* b_hi = (const float*)d_in[7];
  const float* Wfc  = (const float*)d_in[8];
  const float* b_fc = (const float*)d_in[9];

  // ws: rings (3 lay x 16 rg x RD x 16KB = 6 MB) | flags 64KB | hfinal 512KB
  unsigned short* ring = (unsigned short*)d_ws;
  const size_t ring_bytes = (size_t)3 * NRG * RD * MR * NN * 2;  // 6 MB
  unsigned* cnt = (unsigned*)((char*)d_ws + ring_bytes);
  float* hfinal = (float*)((char*)d_ws + ring_bytes + 65536);

  hipMemsetAsync(cnt, 0, 65536, stream);   // flags MUST start at 0 (ws is poisoned)
  hipLaunchKernelGGL(rnn_pipe, dim3(192), dim3(512), 0, stream,
                     data, h0, Win, b_in, Whh, b_hh, Whi, b_hi, ring, cnt, hfinal);
  hipLaunchKernelGGL(readout_k, dim3(256), dim3(64), 0, stream,
                     hfinal, Wfc, b_fc, (float*)d_out);
}